// Round 6
// baseline (206.580 us; speedup 1.0000x reference)
//
#include <hip/hip_runtime.h>
#include <math.h>

#define HEADS 16
#define DH    64
#define SEQ   2048
#define HID   1024
#define NROW  4096

typedef __attribute__((ext_vector_type(8))) short bf16x8;
typedef __attribute__((ext_vector_type(4))) short bf16x4;
typedef __attribute__((ext_vector_type(4))) float f32x4;

#define AS1 __attribute__((address_space(1)))
#define AS3 __attribute__((address_space(3)))

// 0.125 * log2(e): folds softmax scale and exp->exp2 into the Q pack.
#define QSCALE 0.18033688011112042f

__device__ __forceinline__ unsigned short f2bf(float x) {
    unsigned int u = __builtin_bit_cast(unsigned int, x);
    u = (u + 0x7FFFu + ((u >> 16) & 1u)) >> 16;
    return (unsigned short)u;
}

__device__ __forceinline__ void gload_lds16(const unsigned short* g, unsigned short* l) {
    __builtin_amdgcn_global_load_lds((AS1 void*)g, (AS3 void*)l, 16, 0, 0);
}

// ================= prep: conv_x + rope_tab + 2x wtrans in ONE launch =================
__device__ void wtrans_body(const float* __restrict__ wsrc, unsigned short* __restrict__ wt,
                            int K, int N, int bx, int by, float (*T)[65])
{
    const int tid = threadIdx.x;
    const int k0 = by * 64, n0 = bx * 64;
    #pragma unroll
    for (int rnd = 0; rnd < 4; ++rnd) {
        int row = (tid >> 4) + rnd * 16;
        int c = (tid & 15) * 4;
        float4 v = *(const float4*)&wsrc[(size_t)(k0 + row) * N + n0 + c];
        T[row][c] = v.x; T[row][c+1] = v.y; T[row][c+2] = v.z; T[row][c+3] = v.w;
    }
    __syncthreads();
    const int sr = tid >> 3, sc = (tid & 7) << 3;
    #pragma unroll
    for (int half = 0; half < 2; ++half) {
        int n = sr + half * 32;
        union { unsigned short u[8]; bf16x8 v; } pk;
        #pragma unroll
        for (int j = 0; j < 8; ++j) pk.u[j] = f2bf(T[sc + j][n]);
        *(bf16x8*)&wt[(size_t)(n0 + n) * K + k0 + sc] = pk.v;
    }
}

__global__ __launch_bounds__(256) void prep(const float* __restrict__ x,
                                            const float* __restrict__ rot,
                                            const float* __restrict__ w_qkv,
                                            const float* __restrict__ w_out,
                                            unsigned short* __restrict__ xb,
                                            float2* __restrict__ ctab,
                                            unsigned short* __restrict__ wqkvT,
                                            unsigned short* __restrict__ woutT)
{
    __shared__ float T[64][65];
    const int bid = blockIdx.x;
    if (bid < 2048) {
        size_t i = ((size_t)bid * 256 + threadIdx.x) * 8;
        float4 a = *(const float4*)&x[i];
        float4 b = *(const float4*)&x[i + 4];
        union { unsigned short u[8]; bf16x8 v; } pk;
        pk.u[0] = f2bf(a.x); pk.u[1] = f2bf(a.y); pk.u[2] = f2bf(a.z); pk.u[3] = f2bf(a.w);
        pk.u[4] = f2bf(b.x); pk.u[5] = f2bf(b.y); pk.u[6] = f2bf(b.z); pk.u[7] = f2bf(b.w);
        *(bf16x8*)&xb[i] = pk.v;
    } else if (bid < 2560) {
        int i = (bid - 2048) * 256 + threadIdx.x;   // SEQ*DH = 131072
        float r = rot[i];
        float s, c;
        __sincosf(r, &s, &c);
        ctab[i] = make_float2(c, s);
    } else if (bid < 3328) {
        int idx = bid - 2560;                       // 48 x 16
        wtrans_body(w_qkv, wqkvT, 1024, 3072, idx % 48, idx / 48, T);
    } else {
        int idx = bid - 3328;                       // 16 x 16
        wtrans_body(w_out, woutT, 1024, 1024, idx % 16, idx / 16, T);
    }
}

// ========== QKV GEMM v4: A operand direct global->VGPR; only B staged in LDS ==========
// r4 post-mortem: at 6 blocks/CU and 0 conflicts, duration barely moved (57->53) and
// MfmaUtil stayed ~18%: the LDS pipe was ~50% of every iteration (36 KB/iter/block),
// and 2/3 of that traffic was the A tile -- which is WAVE-PRIVATE in this tiling
// (each wave owns rows [wr,wr+32) x all 64 cols). Staging wave-private data through
// LDS is pure overhead. v4: A fragments load straight into registers (the global
// bf16x8 at (row)*1024 + k0 + quad*8 IS the mfma A-fragment, same as attn's Q load);
// B (shared by all 4 waves) keeps the proven swizzled LDS staging. LDS traffic/iter
// -67%, barrier drain covers 1 DMA not 3, LDS footprint 12 KB -> 4 KB.
// A re-reads hit L2: the 48 consecutive blocks sharing an A panel land on the same
// XCDs' L2s (256 KB panel, 4 MB L2).
// V written TILED+SWIZZLED: vt[bh][t][d][ks'] with ks' = ((ks>>2) ^ (d&7))<<2.
__global__ __launch_bounds__(256, 6) void gemm_qkv(const unsigned short* __restrict__ A,
                                                   const unsigned short* __restrict__ Bt,
                                                   const float2* __restrict__ ctab,
                                                   unsigned short* __restrict__ qb,
                                                   unsigned short* __restrict__ kb,
                                                   unsigned short* __restrict__ vt)
{
    __shared__ __align__(16) unsigned short Bs[64 * 32];    // 4 KB
    const int tid = threadIdx.x;
    const int w = tid >> 6, lane = tid & 63;
    const int quad = lane >> 4, lm = lane & 15;
    const int wr = w * 32;                                  // wave rows [wr, wr+32)
    const int bm = blockIdx.y * 128, bn = blockIdx.x * 64;
    const int m0 = tid >> 2;
    const int sk = (((tid & 3) ^ ((m0 >> 1) & 3)) << 3);    // chunk-swizzled source offset
    const int kx = ((quad ^ ((lm >> 1) & 3)) << 3);         // swizzled fragment read chunk

    // A fragment base pointers (per-thread, advance by k0)
    const unsigned short* a0 = A + (size_t)(bm + wr + lm) * 1024 + quad * 8;
    const unsigned short* a1 = a0 + (size_t)16 * 1024;

    f32x4 acc[2][4];
    #pragma unroll
    for (int i = 0; i < 2; ++i)
        #pragma unroll
        for (int j = 0; j < 4; ++j) acc[i][j] = (f32x4){0.f, 0.f, 0.f, 0.f};

    for (int k0 = 0; k0 < 1024; k0 += 32) {
        __syncthreads();
        gload_lds16(&Bt[(size_t)(bn + m0) * 1024 + k0 + sk], Bs + w * 512);
        bf16x8 af[2];
        af[0] = *(const bf16x8*)(a0 + k0);
        af[1] = *(const bf16x8*)(a1 + k0);
        __syncthreads();
        bf16x8 bfr[4];
        #pragma unroll
        for (int nt = 0; nt < 4; ++nt) bfr[nt] = *(const bf16x8*)&Bs[(nt * 16 + lm) * 32 + kx];
        #pragma unroll
        for (int mt = 0; mt < 2; ++mt)
            #pragma unroll
            for (int nt = 0; nt < 4; ++nt)
                acc[mt][nt] = __builtin_amdgcn_mfma_f32_16x16x32_bf16(af[mt], bfr[nt], acc[mt][nt], 0, 0, 0);
    }

    const int colbase = bn;                // 64-col block = one (region, head) slice
    const int region = colbase >> 10;      // 0=q, 1=k, 2=v
    const int h = (colbase >> 6) & 15;

    if (region == 2) {
        #pragma unroll
        for (int mt = 0; mt < 2; ++mt) {
            int rowb = bm + wr + mt * 16 + quad * 4;
            int b = rowb >> 11, seq = rowb & (SEQ - 1);
            int t = seq >> 5, ks = seq & 31;            // ks is a multiple of 4
            #pragma unroll
            for (int nt = 0; nt < 4; ++nt) {
                int d = nt * 16 + lm;
                int ksw = (((ks >> 2) ^ (lm & 7)) << 2);   // slot-level XOR swizzle
                ushort4 pk;
                pk.x = f2bf(acc[mt][nt][0]); pk.y = f2bf(acc[mt][nt][1]);
                pk.z = f2bf(acc[mt][nt][2]); pk.w = f2bf(acc[mt][nt][3]);
                *(ushort4*)&vt[(((size_t)(b * HEADS + h) * 64 + t) * 64 + d) * 32 + ksw] = pk;
            }
        }
    } else {
        const float qs = (region == 0) ? QSCALE : 1.0f;
        unsigned short* dst = (region == 0) ? qb : kb;
        #pragma unroll
        for (int mt = 0; mt < 2; ++mt) {
            #pragma unroll
            for (int nt = 0; nt < 2; ++nt) {
                int d = nt * 16 + lm;
                #pragma unroll
                for (int r = 0; r < 4; ++r) {
                    int row = bm + wr + mt * 16 + quad * 4 + r;
                    int b = row >> 11, seq = row & (SEQ - 1);
                    float2 cs0 = ctab[seq * DH + d];
                    float2 cs1 = ctab[seq * DH + d + 32];
                    float x0 = acc[mt][nt][r];
                    float x1 = acc[mt][nt + 2][r];
                    size_t ob = ((size_t)(b * HEADS + h) * SEQ + seq) * DH;
                    dst[ob + d]      = f2bf((x0 * cs0.x - x1 * cs0.y) * qs);
                    dst[ob + d + 32] = f2bf((x1 * cs1.x + x0 * cs1.y) * qs);
                }
            }
        }
    }
}

// ========== Flash attention v13: v12 (TLP + register-P) + V slot-swizzle ==========
// r1 post-mortem: v12's ds_read_b64 V reads were 8-way bank-conflicted (lm strides 64B;
// SQ_LDS_BANK_CONFLICT 29.4e6 = ~59% of CU-cycles). Fix: V is stored slot-swizzled by
// the producer (see gemm_qkv), staging is a linear memcpy, read XORs the same (lm&7).
// lm and lm+8 still pair (2-way) which is free (m136). Everything else identical to v12.
__global__ __launch_bounds__(256, 4) void attn13(const unsigned short* __restrict__ qb,
                                                 const unsigned short* __restrict__ kb,
                                                 const unsigned short* __restrict__ vt,
                                                 unsigned short* __restrict__ attnb)
{
    __shared__ __align__(16) char smem[32768];
    unsigned short* Ks = (unsigned short*)smem;             // [2 buf][64 kseq][64 d] swizzled rows
    unsigned short* Vs = (unsigned short*)(smem + 16384);   // [2 buf][2 t][64 d][32 ks'] slot-swizzled

    const int tid = threadIdx.x;
    const int w = tid >> 6, lane = tid & 63, quad = lane >> 4, lm = lane & 15;
    const int qg = w >> 1, kg = w & 1;

    // XCD-aware remap: all 32 q-tiles of one bh land on one XCD (linear L = x + 32y).
    // Per-XCD K/V working set = 4 bh x 512 KB = 2 MB < 4 MB L2.
    const int L = blockIdx.x + blockIdx.y * 32;
    const int bh = (L & 7) + 8 * ((L >> 3) & 3);
    const int q0 = (L >> 5) * 64;

    const int b = bh >> 4, h = bh & 15;
    const size_t hb = (size_t)bh * SEQ * DH;

    // Q fragments: wave's 32 q rows (B-operand: lane q=lm, k = c*32+quad*8+j)
    bf16x8 qf[2][2];
    #pragma unroll
    for (int qt = 0; qt < 2; ++qt)
        #pragma unroll
        for (int c = 0; c < 2; ++c)
            qf[qt][c] = *(const bf16x8*)&qb[hb + (size_t)(q0 + qg * 32 + qt * 16 + lm) * DH + c * 32 + quad * 8];

    // --- staging lane constants (identical to attn9) ---
    const int r0 = (w * 16) + (lane >> 3);
    const int p0 = lane & 7;
    const int gk0 = r0 * 64 + (p0 ^ (r0 & 7)) * 8;          // pre-swizzled global src, n=0
    const int r1 = r0 + 8;
    const int gk1 = r1 * 64 + (p0 ^ (r1 & 7)) * 8;          // n=1
    const unsigned short* kgp = kb + hb;
    const unsigned short* vgp = vt + hb;                     // tiled+swizzled [t][64][32]
    const int gv0 = w * 1024 + lane * 8;
    const int gv1 = gv0 + 512;
    unsigned short* kdst0 = Ks + w * 1024;
    unsigned short* kdst1 = Ks + w * 1024 + 512;
    unsigned short* vdst0 = Vs + w * 1024;
    unsigned short* vdst1 = Vs + w * 1024 + 512;

    // --- frag read offsets (elements, relative to buffer base) ---
    int kfo[2];
    #pragma unroll
    for (int c = 0; c < 2; ++c)
        kfo[c] = (kg * 32 + lm) * 64 + (((c * 4 + quad) ^ (lm & 7)) * 8);
    const int vrow = kg * 2048 + lm * 32;                    // + dt*512 + swizzled slot

    float rs[2] = {0.f, 0.f};
    f32x4 o[2][4];
    #pragma unroll
    for (int qt = 0; qt < 2; ++qt)
        #pragma unroll
        for (int dt = 0; dt < 4; ++dt) o[qt][dt] = (f32x4){0.f, 0.f, 0.f, 0.f};

    // prime: DMA tile 0 into buf 0
    gload_lds16(kgp + gk0, kdst0);
    gload_lds16(kgp + gk1, kdst1);
    gload_lds16(vgp + gv0, vdst0);
    gload_lds16(vgp + gv1, vdst1);

    #pragma unroll 2
    for (int it = 0; it < 32; ++it) {
        const int buf = it & 1;
        __syncthreads();   // drains vmcnt(0): DMA(it) visible; buf^1 free to overwrite
        {
            const size_t nb = (size_t)((it + 1) & 31) * 4096;  // tile base in elements
            const int bo = (buf ^ 1) * 4096;
            gload_lds16(kgp + nb + gk0, kdst0 + bo);
            gload_lds16(kgp + nb + gk1, kdst1 + bo);
            gload_lds16(vgp + nb + gv0, vdst0 + bo);
            gload_lds16(vgp + nb + gv1, vdst1 + bo);
        }
        const unsigned short* Kb = Ks + buf * 4096;
        const unsigned short* Vb = Vs + buf * 4096;

        #pragma unroll
        for (int kt = 0; kt < 2; ++kt) {
            bf16x8 k0 = *(const bf16x8*)&Kb[kfo[0] + kt * 1024];
            bf16x8 k1 = *(const bf16x8*)&Kb[kfo[1] + kt * 1024];
            bf16x4 vb[4];
            #pragma unroll
            for (int dt = 0; dt < 4; ++dt)
                vb[dt] = *(const bf16x4*)&Vb[vrow + dt * 512 + (((kt * 4 + quad) ^ (lm & 7)) << 2)];
            f32x4 s[2];
            #pragma unroll
            for (int qt = 0; qt < 2; ++qt) {
                f32x4 z = (f32x4){0.f, 0.f, 0.f, 0.f};
                z = __builtin_amdgcn_mfma_f32_16x16x32_bf16(k0, qf[qt][0], z, 0, 0, 0);
                s[qt] = __builtin_amdgcn_mfma_f32_16x16x32_bf16(k1, qf[qt][1], z, 0, 0, 0);
            }
            #pragma unroll
            for (int qt = 0; qt < 2; ++qt) {
                unsigned int u[4];
                #pragma unroll
                for (int r = 0; r < 4; ++r) {
                    float p = __builtin_amdgcn_exp2f(s[qt][r]);
                    rs[qt] += p;
                    u[r] = __builtin_bit_cast(unsigned int, p);
                }
                union { unsigned int w2[2]; bf16x4 v; } pk;
                pk.w2[0] = __builtin_amdgcn_perm(u[1], u[0], 0x07060302);
                pk.w2[1] = __builtin_amdgcn_perm(u[3], u[2], 0x07060302);
                // P fragment is already in A-operand layout for K=16 MFMA: row=q=lm,
                // k=quad*4+{0..3}. Accumulate PV directly, no LDS round-trip.
                #pragma unroll
                for (int dt = 0; dt < 4; ++dt)
                    o[qt][dt] = __builtin_amdgcn_mfma_f32_16x16x16bf16_1k(pk.v, vb[dt], o[qt][dt], 0, 0, 0);
            }
        }
    }

    // quad-reduce rs (full row-sum for q=lm in every lane)
    #pragma unroll
    for (int off = 16; off < 64; off <<= 1)
        #pragma unroll
        for (int qt = 0; qt < 2; ++qt) rs[qt] += __shfl_xor(rs[qt], off, 64);

    // ---- merge the 2 k-groups (linear softmax: plain add) ----
    __syncthreads();   // drains last dummy DMA before overlaying smem
    float* oBuf = (float*)smem;                  // [64 q][68] floats = 17408 B (overlays Ks/Vs)
    float* lRed = (float*)(smem + 17408);        // [64]
    if (kg == 1) {
        #pragma unroll
        for (int qt = 0; qt < 2; ++qt)
            #pragma unroll
            for (int dt = 0; dt < 4; ++dt)
                #pragma unroll
                for (int r = 0; r < 4; ++r)
                    oBuf[(qg * 32 + qt * 16 + quad * 4 + r) * 68 + dt * 16 + lm] = o[qt][dt][r];
        if (quad == 0) {
            #pragma unroll
            for (int qt = 0; qt < 2; ++qt) lRed[qg * 32 + qt * 16 + lm] = rs[qt];
        }
    }
    __syncthreads();
    if (kg == 0) {
        #pragma unroll
        for (int qt = 0; qt < 2; ++qt) {
            rs[qt] += lRed[qg * 32 + qt * 16 + lm];
            #pragma unroll
            for (int dt = 0; dt < 4; ++dt)
                #pragma unroll
                for (int r = 0; r < 4; ++r)
                    o[qt][dt][r] += oBuf[(qg * 32 + qt * 16 + quad * 4 + r) * 68 + dt * 16 + lm];
        }
        #pragma unroll
        for (int qt = 0; qt < 2; ++qt)
            #pragma unroll
            for (int r = 0; r < 4; ++r) {
                float inv = 1.0f / __shfl(rs[qt], quad * 4 + r, 64);
                int row = b * SEQ + q0 + qg * 32 + qt * 16 + quad * 4 + r;
                #pragma unroll
                for (int dt = 0; dt < 4; ++dt)
                    attnb[(size_t)row * HID + h * DH + dt * 16 + lm] = f2bf(o[qt][dt][r] * inv);
            }
    }
}

// ========== output GEMM v2: 64x128 tiles, double-buffered single-barrier + swizzle ==========
__global__ __launch_bounds__(256) void gemm_out(const unsigned short* __restrict__ A,
                                                const unsigned short* __restrict__ Bt,
                                                float* __restrict__ C)
{
    __shared__ __align__(16) unsigned short As[2][64 * 32];
    __shared__ __align__(16) unsigned short Bs[2][128 * 32];
    const int tid = threadIdx.x;
    const int w = tid >> 6, lane = tid & 63;
    const int quad = lane >> 4, lm = lane & 15;
    const int wr = (w >> 1) * 32, wc = (w & 1) * 64;
    const int bm = blockIdx.y * 64, bn = blockIdx.x * 128;
    const int m0 = tid >> 2;
    const int sk = (((tid & 3) ^ ((m0 >> 1) & 3)) << 3);   // chunk-swizzled source offset
    const int kx = ((quad ^ ((lm >> 1) & 3)) << 3);        // swizzled fragment read chunk

    f32x4 acc[2][4];
    #pragma unroll
    for (int i = 0; i < 2; ++i)
        #pragma unroll
        for (int j = 0; j < 4; ++j) acc[i][j] = (f32x4){0.f, 0.f, 0.f, 0.f};

    // prologue: stage k-tile 0 into buf 0
    gload_lds16(&A [(size_t)(bm + m0     ) * 1024 + sk], &As[0][w * 512]);
    gload_lds16(&Bt[(size_t)(bn + m0     ) * 1024 + sk], &Bs[0][w * 512]);
    gload_lds16(&Bt[(size_t)(bn + m0 + 64) * 1024 + sk], &Bs[0][2048 + w * 512]);

    #pragma unroll 2
    for (int it = 0; it < 32; ++it) {
        const int buf = it & 1;
        __syncthreads();
        {
            const int nk = ((it + 1) & 31) * 32;
            gload_lds16(&A [(size_t)(bm + m0     ) * 1024 + nk + sk], &As[buf ^ 1][w * 512]);
            gload_lds16(&Bt[(size_t)(bn + m0     ) * 1024 + nk + sk], &Bs[buf ^ 1][w * 512]);
            gload_lds16(&Bt[(size_t)(bn + m0 + 64) * 1024 + nk + sk], &Bs[buf ^ 1][2048 + w * 512]);
        }
        bf16x8 af[2], bfr[4];
        #pragma unroll
        for (int mt = 0; mt < 2; ++mt) af[mt] = *(const bf16x8*)&As[buf][(wr + mt * 16 + lm) * 32 + kx];
        #pragma unroll
        for (int nt = 0; nt < 4; ++nt) bfr[nt] = *(const bf16x8*)&Bs[buf][(wc + nt * 16 + lm) * 32 + kx];
        #pragma unroll
        for (int mt = 0; mt < 2; ++mt)
            #pragma unroll
            for (int nt = 0; nt < 4; ++nt)
                acc[mt][nt] = __builtin_amdgcn_mfma_f32_16x16x32_bf16(af[mt], bfr[nt], acc[mt][nt], 0, 0, 0);
    }

    #pragma unroll
    for (int mt = 0; mt < 2; ++mt)
        #pragma unroll
        for (int nt = 0; nt < 4; ++nt) {
            int col = bn + wc + nt * 16 + lm;
            #pragma unroll
            for (int r = 0; r < 4; ++r) {
                int row = bm + wr + mt * 16 + quad * 4 + r;
                C[(size_t)row * 1024 + col] = acc[mt][nt][r];
            }
        }
}

extern "C" void kernel_launch(void* const* d_in, const int* in_sizes, int n_in,
                              void* d_out, int out_size, void* d_ws, size_t ws_size,
                              hipStream_t stream) {
    const float* x     = (const float*)d_in[0];
    const float* rot   = (const float*)d_in[1];
    const float* w_qkv = (const float*)d_in[2];
    const float* w_out = (const float*)d_in[3];
    float* out = (float*)d_out;

    char* ws = (char*)d_ws;
    unsigned short* xb    = (unsigned short*)(ws);                         // 8 MB
    unsigned short* qb    = (unsigned short*)(ws + (size_t)( 8u << 20));   // 8 MB [bh][seq][64]
    unsigned short* kb    = (unsigned short*)(ws + (size_t)(16u << 20));   // 8 MB [bh][seq][64]
    unsigned short* vt    = (unsigned short*)(ws + (size_t)(24u << 20));   // 8 MB [bh][seq/32][64][32] slot-swizzled
    unsigned short* attnb = (unsigned short*)(ws + (size_t)(32u << 20));   // 8 MB
    unsigned short* wqkvT = (unsigned short*)(ws + (size_t)(40u << 20));   // 6 MB
    unsigned short* woutT = (unsigned short*)(ws + (size_t)(46u << 20));   // 2 MB
    float2*         ctab  = (float2*)        (ws + (size_t)(48u << 20));   // 1 MB

    prep<<<3584, 256, 0, stream>>>(x, rot, w_qkv, w_out, xb, ctab, wqkvT, woutT);

    gemm_qkv<<<dim3(48, 32), 256, 0, stream>>>(xb, wqkvT, ctab, qb, kb, vt);

    attn13<<<dim3(32, 32), 256, 0, stream>>>(qb, kb, vt, attnb);

    gemm_out<<<dim3(8, 64), 256, 0, stream>>>(attnb, woutT, out);
}

// Round 7
// 192.774 us; speedup vs baseline: 1.0716x; 1.0716x over previous
//
#include <hip/hip_runtime.h>
#include <math.h>

#define HEADS 16
#define DH    64
#define SEQ   2048
#define HID   1024
#define NROW  4096

typedef __attribute__((ext_vector_type(8))) short bf16x8;
typedef __attribute__((ext_vector_type(4))) short bf16x4;
typedef __attribute__((ext_vector_type(4))) float f32x4;

#define AS1 __attribute__((address_space(1)))
#define AS3 __attribute__((address_space(3)))

// 0.125 * log2(e): folds softmax scale and exp->exp2 into the Q pack.
#define QSCALE 0.18033688011112042f

__device__ __forceinline__ unsigned short f2bf(float x) {
    unsigned int u = __builtin_bit_cast(unsigned int, x);
    u = (u + 0x7FFFu + ((u >> 16) & 1u)) >> 16;
    return (unsigned short)u;
}

__device__ __forceinline__ void gload_lds16(const unsigned short* g, unsigned short* l) {
    __builtin_amdgcn_global_load_lds((AS1 void*)g, (AS3 void*)l, 16, 0, 0);
}

// ================= prep: conv_x + rope_tab + 2x wtrans in ONE launch =================
__device__ void wtrans_body(const float* __restrict__ wsrc, unsigned short* __restrict__ wt,
                            int K, int N, int bx, int by, float (*T)[65])
{
    const int tid = threadIdx.x;
    const int k0 = by * 64, n0 = bx * 64;
    #pragma unroll
    for (int rnd = 0; rnd < 4; ++rnd) {
        int row = (tid >> 4) + rnd * 16;
        int c = (tid & 15) * 4;
        float4 v = *(const float4*)&wsrc[(size_t)(k0 + row) * N + n0 + c];
        T[row][c] = v.x; T[row][c+1] = v.y; T[row][c+2] = v.z; T[row][c+3] = v.w;
    }
    __syncthreads();
    const int sr = tid >> 3, sc = (tid & 7) << 3;
    #pragma unroll
    for (int half = 0; half < 2; ++half) {
        int n = sr + half * 32;
        union { unsigned short u[8]; bf16x8 v; } pk;
        #pragma unroll
        for (int j = 0; j < 8; ++j) pk.u[j] = f2bf(T[sc + j][n]);
        *(bf16x8*)&wt[(size_t)(n0 + n) * K + k0 + sc] = pk.v;
    }
}

__global__ __launch_bounds__(256) void prep(const float* __restrict__ x,
                                            const float* __restrict__ rot,
                                            const float* __restrict__ w_qkv,
                                            const float* __restrict__ w_out,
                                            unsigned short* __restrict__ xb,
                                            float2* __restrict__ ctab,
                                            unsigned short* __restrict__ wqkvT,
                                            unsigned short* __restrict__ woutT)
{
    __shared__ float T[64][65];
    const int bid = blockIdx.x;
    if (bid < 2048) {
        size_t i = ((size_t)bid * 256 + threadIdx.x) * 8;
        float4 a = *(const float4*)&x[i];
        float4 b = *(const float4*)&x[i + 4];
        union { unsigned short u[8]; bf16x8 v; } pk;
        pk.u[0] = f2bf(a.x); pk.u[1] = f2bf(a.y); pk.u[2] = f2bf(a.z); pk.u[3] = f2bf(a.w);
        pk.u[4] = f2bf(b.x); pk.u[5] = f2bf(b.y); pk.u[6] = f2bf(b.z); pk.u[7] = f2bf(b.w);
        *(bf16x8*)&xb[i] = pk.v;
    } else if (bid < 2560) {
        int i = (bid - 2048) * 256 + threadIdx.x;   // SEQ*DH = 131072
        float r = rot[i];
        float s, c;
        __sincosf(r, &s, &c);
        ctab[i] = make_float2(c, s);
    } else if (bid < 3328) {
        int idx = bid - 2560;                       // 48 x 16
        wtrans_body(w_qkv, wqkvT, 1024, 3072, idx % 48, idx / 48, T);
    } else {
        int idx = bid - 3328;                       // 16 x 16
        wtrans_body(w_out, woutT, 1024, 1024, idx % 16, idx / 16, T);
    }
}

// ========== QKV GEMM v5: back to LDS-staged A/B (r5 post-mortem: A-fragments are
// row-scattered by construction -> direct global reads explode TA request rate), with
// BK=64 to halve the barrier/drain count (32 -> 16 iters; bytes/K unchanged).
// 64-col rows wrap all 32 banks, so use attn9's PROVEN 8-chunk XOR swizzle:
// staging source chunk (lane&7)^(row&7) with linear LDS dest (guideline 21), read
// chunk ((c*4+quad)^(lm&7)). 24 KB LDS, launch_bounds(256,5) -> 5 blocks/CU, no spill.
// V written TILED+SWIZZLED: vt[bh][t][d][ks'] with ks' = ((ks>>2) ^ (d&7))<<2.
__global__ __launch_bounds__(256, 5) void gemm_qkv(const unsigned short* __restrict__ A,
                                                   const unsigned short* __restrict__ Bt,
                                                   const float2* __restrict__ ctab,
                                                   unsigned short* __restrict__ qb,
                                                   unsigned short* __restrict__ kb,
                                                   unsigned short* __restrict__ vt)
{
    __shared__ __align__(16) unsigned short As[128 * 64];   // 16 KB, row-XOR swizzled
    __shared__ __align__(16) unsigned short Bs[64 * 64];    // 8 KB
    const int tid = threadIdx.x;
    const int w = tid >> 6, lane = tid & 63;
    const int quad = lane >> 4, lm = lane & 15;
    const int wr = w * 32;                                  // wave rows [wr, wr+32)
    const int bm = blockIdx.y * 128, bn = blockIdx.x * 64;

    // staging constants (attn9 pattern): each gload covers 32 rows x 64 cols
    const int ga = w * 8 + (lane >> 3);                     // row within 32-row group
    const int gp = ((lane & 7) ^ (lane >> 3)) << 3;         // pre-swizzled source chunk

    // fragment read chunk offsets for the two K=32 halves
    int cko[2];
    #pragma unroll
    for (int c = 0; c < 2; ++c)
        cko[c] = (((c * 4 + quad) ^ (lm & 7)) << 3);

    f32x4 acc[2][4];
    #pragma unroll
    for (int i = 0; i < 2; ++i)
        #pragma unroll
        for (int j = 0; j < 4; ++j) acc[i][j] = (f32x4){0.f, 0.f, 0.f, 0.f};

    for (int k0 = 0; k0 < 1024; k0 += 64) {
        __syncthreads();
        #pragma unroll
        for (int i = 0; i < 4; ++i)
            gload_lds16(&A[(size_t)(bm + i * 32 + ga) * 1024 + k0 + gp], As + i * 2048 + w * 512);
        #pragma unroll
        for (int i = 0; i < 2; ++i)
            gload_lds16(&Bt[(size_t)(bn + i * 32 + ga) * 1024 + k0 + gp], Bs + i * 2048 + w * 512);
        __syncthreads();
        bf16x8 af[2][2], bfr[4][2];
        #pragma unroll
        for (int mt = 0; mt < 2; ++mt)
            #pragma unroll
            for (int c = 0; c < 2; ++c)
                af[mt][c] = *(const bf16x8*)&As[(wr + mt * 16 + lm) * 64 + cko[c]];
        #pragma unroll
        for (int nt = 0; nt < 4; ++nt)
            #pragma unroll
            for (int c = 0; c < 2; ++c)
                bfr[nt][c] = *(const bf16x8*)&Bs[(nt * 16 + lm) * 64 + cko[c]];
        #pragma unroll
        for (int mt = 0; mt < 2; ++mt)
            #pragma unroll
            for (int nt = 0; nt < 4; ++nt) {
                acc[mt][nt] = __builtin_amdgcn_mfma_f32_16x16x32_bf16(af[mt][0], bfr[nt][0], acc[mt][nt], 0, 0, 0);
                acc[mt][nt] = __builtin_amdgcn_mfma_f32_16x16x32_bf16(af[mt][1], bfr[nt][1], acc[mt][nt], 0, 0, 0);
            }
    }

    const int colbase = bn;                // 64-col block = one (region, head) slice
    const int region = colbase >> 10;      // 0=q, 1=k, 2=v
    const int h = (colbase >> 6) & 15;

    if (region == 2) {
        #pragma unroll
        for (int mt = 0; mt < 2; ++mt) {
            int rowb = bm + wr + mt * 16 + quad * 4;
            int b = rowb >> 11, seq = rowb & (SEQ - 1);
            int t = seq >> 5, ks = seq & 31;            // ks is a multiple of 4
            #pragma unroll
            for (int nt = 0; nt < 4; ++nt) {
                int d = nt * 16 + lm;
                int ksw = (((ks >> 2) ^ (lm & 7)) << 2);   // slot-level XOR swizzle
                ushort4 pk;
                pk.x = f2bf(acc[mt][nt][0]); pk.y = f2bf(acc[mt][nt][1]);
                pk.z = f2bf(acc[mt][nt][2]); pk.w = f2bf(acc[mt][nt][3]);
                *(ushort4*)&vt[(((size_t)(b * HEADS + h) * 64 + t) * 64 + d) * 32 + ksw] = pk;
            }
        }
    } else {
        const float qs = (region == 0) ? QSCALE : 1.0f;
        unsigned short* dst = (region == 0) ? qb : kb;
        #pragma unroll
        for (int mt = 0; mt < 2; ++mt) {
            #pragma unroll
            for (int nt = 0; nt < 2; ++nt) {
                int d = nt * 16 + lm;
                #pragma unroll
                for (int r = 0; r < 4; ++r) {
                    int row = bm + wr + mt * 16 + quad * 4 + r;
                    int b = row >> 11, seq = row & (SEQ - 1);
                    float2 cs0 = ctab[seq * DH + d];
                    float2 cs1 = ctab[seq * DH + d + 32];
                    float x0 = acc[mt][nt][r];
                    float x1 = acc[mt][nt + 2][r];
                    size_t ob = ((size_t)(b * HEADS + h) * SEQ + seq) * DH;
                    dst[ob + d]      = f2bf((x0 * cs0.x - x1 * cs0.y) * qs);
                    dst[ob + d + 32] = f2bf((x1 * cs1.x + x0 * cs1.y) * qs);
                }
            }
        }
    }
}

// ========== Flash attention v13: v12 (TLP + register-P) + V slot-swizzle ==========
// r1 post-mortem: v12's ds_read_b64 V reads were 8-way bank-conflicted (lm strides 64B;
// SQ_LDS_BANK_CONFLICT 29.4e6 = ~59% of CU-cycles). Fix: V is stored slot-swizzled by
// the producer (see gemm_qkv), staging is a linear memcpy, read XORs the same (lm&7).
// lm and lm+8 still pair (2-way) which is free (m136). Everything else identical to v12.
__global__ __launch_bounds__(256, 4) void attn13(const unsigned short* __restrict__ qb,
                                                 const unsigned short* __restrict__ kb,
                                                 const unsigned short* __restrict__ vt,
                                                 unsigned short* __restrict__ attnb)
{
    __shared__ __align__(16) char smem[32768];
    unsigned short* Ks = (unsigned short*)smem;             // [2 buf][64 kseq][64 d] swizzled rows
    unsigned short* Vs = (unsigned short*)(smem + 16384);   // [2 buf][2 t][64 d][32 ks'] slot-swizzled

    const int tid = threadIdx.x;
    const int w = tid >> 6, lane = tid & 63, quad = lane >> 4, lm = lane & 15;
    const int qg = w >> 1, kg = w & 1;

    // XCD-aware remap: all 32 q-tiles of one bh land on one XCD (linear L = x + 32y).
    // Per-XCD K/V working set = 4 bh x 512 KB = 2 MB < 4 MB L2.
    const int L = blockIdx.x + blockIdx.y * 32;
    const int bh = (L & 7) + 8 * ((L >> 3) & 3);
    const int q0 = (L >> 5) * 64;

    const int b = bh >> 4, h = bh & 15;
    const size_t hb = (size_t)bh * SEQ * DH;

    // Q fragments: wave's 32 q rows (B-operand: lane q=lm, k = c*32+quad*8+j)
    bf16x8 qf[2][2];
    #pragma unroll
    for (int qt = 0; qt < 2; ++qt)
        #pragma unroll
        for (int c = 0; c < 2; ++c)
            qf[qt][c] = *(const bf16x8*)&qb[hb + (size_t)(q0 + qg * 32 + qt * 16 + lm) * DH + c * 32 + quad * 8];

    // --- staging lane constants (identical to attn9) ---
    const int r0 = (w * 16) + (lane >> 3);
    const int p0 = lane & 7;
    const int gk0 = r0 * 64 + (p0 ^ (r0 & 7)) * 8;          // pre-swizzled global src, n=0
    const int r1 = r0 + 8;
    const int gk1 = r1 * 64 + (p0 ^ (r1 & 7)) * 8;          // n=1
    const unsigned short* kgp = kb + hb;
    const unsigned short* vgp = vt + hb;                     // tiled+swizzled [t][64][32]
    const int gv0 = w * 1024 + lane * 8;
    const int gv1 = gv0 + 512;
    unsigned short* kdst0 = Ks + w * 1024;
    unsigned short* kdst1 = Ks + w * 1024 + 512;
    unsigned short* vdst0 = Vs + w * 1024;
    unsigned short* vdst1 = Vs + w * 1024 + 512;

    // --- frag read offsets (elements, relative to buffer base) ---
    int kfo[2];
    #pragma unroll
    for (int c = 0; c < 2; ++c)
        kfo[c] = (kg * 32 + lm) * 64 + (((c * 4 + quad) ^ (lm & 7)) * 8);
    const int vrow = kg * 2048 + lm * 32;                    // + dt*512 + swizzled slot

    float rs[2] = {0.f, 0.f};
    f32x4 o[2][4];
    #pragma unroll
    for (int qt = 0; qt < 2; ++qt)
        #pragma unroll
        for (int dt = 0; dt < 4; ++dt) o[qt][dt] = (f32x4){0.f, 0.f, 0.f, 0.f};

    // prime: DMA tile 0 into buf 0
    gload_lds16(kgp + gk0, kdst0);
    gload_lds16(kgp + gk1, kdst1);
    gload_lds16(vgp + gv0, vdst0);
    gload_lds16(vgp + gv1, vdst1);

    #pragma unroll 2
    for (int it = 0; it < 32; ++it) {
        const int buf = it & 1;
        __syncthreads();   // drains vmcnt(0): DMA(it) visible; buf^1 free to overwrite
        {
            const size_t nb = (size_t)((it + 1) & 31) * 4096;  // tile base in elements
            const int bo = (buf ^ 1) * 4096;
            gload_lds16(kgp + nb + gk0, kdst0 + bo);
            gload_lds16(kgp + nb + gk1, kdst1 + bo);
            gload_lds16(vgp + nb + gv0, vdst0 + bo);
            gload_lds16(vgp + nb + gv1, vdst1 + bo);
        }
        const unsigned short* Kb = Ks + buf * 4096;
        const unsigned short* Vb = Vs + buf * 4096;

        #pragma unroll
        for (int kt = 0; kt < 2; ++kt) {
            bf16x8 k0 = *(const bf16x8*)&Kb[kfo[0] + kt * 1024];
            bf16x8 k1 = *(const bf16x8*)&Kb[kfo[1] + kt * 1024];
            bf16x4 vb[4];
            #pragma unroll
            for (int dt = 0; dt < 4; ++dt)
                vb[dt] = *(const bf16x4*)&Vb[vrow + dt * 512 + (((kt * 4 + quad) ^ (lm & 7)) << 2)];
            f32x4 s[2];
            #pragma unroll
            for (int qt = 0; qt < 2; ++qt) {
                f32x4 z = (f32x4){0.f, 0.f, 0.f, 0.f};
                z = __builtin_amdgcn_mfma_f32_16x16x32_bf16(k0, qf[qt][0], z, 0, 0, 0);
                s[qt] = __builtin_amdgcn_mfma_f32_16x16x32_bf16(k1, qf[qt][1], z, 0, 0, 0);
            }
            #pragma unroll
            for (int qt = 0; qt < 2; ++qt) {
                unsigned int u[4];
                #pragma unroll
                for (int r = 0; r < 4; ++r) {
                    float p = __builtin_amdgcn_exp2f(s[qt][r]);
                    rs[qt] += p;
                    u[r] = __builtin_bit_cast(unsigned int, p);
                }
                union { unsigned int w2[2]; bf16x4 v; } pk;
                pk.w2[0] = __builtin_amdgcn_perm(u[1], u[0], 0x07060302);
                pk.w2[1] = __builtin_amdgcn_perm(u[3], u[2], 0x07060302);
                // P fragment is already in A-operand layout for K=16 MFMA: row=q=lm,
                // k=quad*4+{0..3}. Accumulate PV directly, no LDS round-trip.
                #pragma unroll
                for (int dt = 0; dt < 4; ++dt)
                    o[qt][dt] = __builtin_amdgcn_mfma_f32_16x16x16bf16_1k(pk.v, vb[dt], o[qt][dt], 0, 0, 0);
            }
        }
    }

    // quad-reduce rs (full row-sum for q=lm in every lane)
    #pragma unroll
    for (int off = 16; off < 64; off <<= 1)
        #pragma unroll
        for (int qt = 0; qt < 2; ++qt) rs[qt] += __shfl_xor(rs[qt], off, 64);

    // ---- merge the 2 k-groups (linear softmax: plain add) ----
    __syncthreads();   // drains last dummy DMA before overlaying smem
    float* oBuf = (float*)smem;                  // [64 q][68] floats = 17408 B (overlays Ks/Vs)
    float* lRed = (float*)(smem + 17408);        // [64]
    if (kg == 1) {
        #pragma unroll
        for (int qt = 0; qt < 2; ++qt)
            #pragma unroll
            for (int dt = 0; dt < 4; ++dt)
                #pragma unroll
                for (int r = 0; r < 4; ++r)
                    oBuf[(qg * 32 + qt * 16 + quad * 4 + r) * 68 + dt * 16 + lm] = o[qt][dt][r];
        if (quad == 0) {
            #pragma unroll
            for (int qt = 0; qt < 2; ++qt) lRed[qg * 32 + qt * 16 + lm] = rs[qt];
        }
    }
    __syncthreads();
    if (kg == 0) {
        #pragma unroll
        for (int qt = 0; qt < 2; ++qt) {
            rs[qt] += lRed[qg * 32 + qt * 16 + lm];
            #pragma unroll
            for (int dt = 0; dt < 4; ++dt)
                #pragma unroll
                for (int r = 0; r < 4; ++r)
                    o[qt][dt][r] += oBuf[(qg * 32 + qt * 16 + quad * 4 + r) * 68 + dt * 16 + lm];
        }
        #pragma unroll
        for (int qt = 0; qt < 2; ++qt)
            #pragma unroll
            for (int r = 0; r < 4; ++r) {
                float inv = 1.0f / __shfl(rs[qt], quad * 4 + r, 64);
                int row = b * SEQ + q0 + qg * 32 + qt * 16 + quad * 4 + r;
                #pragma unroll
                for (int dt = 0; dt < 4; ++dt)
                    attnb[(size_t)row * HID + h * DH + dt * 16 + lm] = f2bf(o[qt][dt][r] * inv);
            }
    }
}

// ========== output GEMM v3: 64x64 tiles (4 blocks/CU TLP), dbuf + chunk swizzle ==========
// r4's TLP lever applied to gemm_out: grid 512 -> 1024 blocks (2 -> 4 blocks/CU).
// Keeps the dbuf single-barrier pipeline that already helped this kernel in r3 (-7.5 us).
__global__ __launch_bounds__(256, 4) void gemm_out(const unsigned short* __restrict__ A,
                                                   const unsigned short* __restrict__ Bt,
                                                   float* __restrict__ C)
{
    __shared__ __align__(16) unsigned short As[2][64 * 32];
    __shared__ __align__(16) unsigned short Bs[2][64 * 32];
    const int tid = threadIdx.x;
    const int w = tid >> 6, lane = tid & 63;
    const int quad = lane >> 4, lm = lane & 15;
    const int wr = w * 16;                                  // wave rows [wr, wr+16)
    const int bm = blockIdx.y * 64, bn = blockIdx.x * 64;
    const int m0 = tid >> 2;
    const int sk = (((tid & 3) ^ ((m0 >> 1) & 3)) << 3);   // chunk-swizzled source offset
    const int kx = ((quad ^ ((lm >> 1) & 3)) << 3);        // swizzled fragment read chunk

    f32x4 acc[4];
    #pragma unroll
    for (int j = 0; j < 4; ++j) acc[j] = (f32x4){0.f, 0.f, 0.f, 0.f};

    // prologue: stage k-tile 0 into buf 0
    gload_lds16(&A [(size_t)(bm + m0) * 1024 + sk], &As[0][w * 512]);
    gload_lds16(&Bt[(size_t)(bn + m0) * 1024 + sk], &Bs[0][w * 512]);

    #pragma unroll 2
    for (int it = 0; it < 32; ++it) {
        const int buf = it & 1;
        __syncthreads();
        {
            const int nk = ((it + 1) & 31) * 32;
            gload_lds16(&A [(size_t)(bm + m0) * 1024 + nk + sk], &As[buf ^ 1][w * 512]);
            gload_lds16(&Bt[(size_t)(bn + m0) * 1024 + nk + sk], &Bs[buf ^ 1][w * 512]);
        }
        bf16x8 af, bfr[4];
        af = *(const bf16x8*)&As[buf][(wr + lm) * 32 + kx];
        #pragma unroll
        for (int nt = 0; nt < 4; ++nt) bfr[nt] = *(const bf16x8*)&Bs[buf][(nt * 16 + lm) * 32 + kx];
        #pragma unroll
        for (int nt = 0; nt < 4; ++nt)
            acc[nt] = __builtin_amdgcn_mfma_f32_16x16x32_bf16(af, bfr[nt], acc[nt], 0, 0, 0);
    }

    #pragma unroll
    for (int nt = 0; nt < 4; ++nt) {
        int col = bn + nt * 16 + lm;
        #pragma unroll
        for (int r = 0; r < 4; ++r) {
            int row = bm + wr + quad * 4 + r;
            C[(size_t)row * 1024 + col] = acc[nt][r];
        }
    }
}

extern "C" void kernel_launch(void* const* d_in, const int* in_sizes, int n_in,
                              void* d_out, int out_size, void* d_ws, size_t ws_size,
                              hipStream_t stream) {
    const float* x     = (const float*)d_in[0];
    const float* rot   = (const float*)d_in[1];
    const float* w_qkv = (const float*)d_in[2];
    const float* w_out = (const float*)d_in[3];
    float* out = (float*)d_out;

    char* ws = (char*)d_ws;
    unsigned short* xb    = (unsigned short*)(ws);                         // 8 MB
    unsigned short* qb    = (unsigned short*)(ws + (size_t)( 8u << 20));   // 8 MB [bh][seq][64]
    unsigned short* kb    = (unsigned short*)(ws + (size_t)(16u << 20));   // 8 MB [bh][seq][64]
    unsigned short* vt    = (unsigned short*)(ws + (size_t)(24u << 20));   // 8 MB [bh][seq/32][64][32] slot-swizzled
    unsigned short* attnb = (unsigned short*)(ws + (size_t)(32u << 20));   // 8 MB
    unsigned short* wqkvT = (unsigned short*)(ws + (size_t)(40u << 20));   // 6 MB
    unsigned short* woutT = (unsigned short*)(ws + (size_t)(46u << 20));   // 2 MB
    float2*         ctab  = (float2*)        (ws + (size_t)(48u << 20));   // 1 MB

    prep<<<3584, 256, 0, stream>>>(x, rot, w_qkv, w_out, xb, ctab, wqkvT, woutT);

    gemm_qkv<<<dim3(48, 32), 256, 0, stream>>>(xb, wqkvT, ctab, qb, kb, vt);

    attn13<<<dim3(32, 32), 256, 0, stream>>>(qb, kb, vt, attnb);

    gemm_out<<<dim3(16, 64), 256, 0, stream>>>(attnb, woutT, out);
}

// Round 9
// 178.545 us; speedup vs baseline: 1.1570x; 1.0797x over previous
//
#include <hip/hip_runtime.h>
#include <math.h>

#define HEADS 16
#define DH    64
#define SEQ   2048
#define HID   1024
#define NROW  4096

typedef __attribute__((ext_vector_type(8))) short bf16x8;
typedef __attribute__((ext_vector_type(4))) short bf16x4;
typedef __attribute__((ext_vector_type(4))) float f32x4;

#define AS1 __attribute__((address_space(1)))
#define AS3 __attribute__((address_space(3)))

// 0.125 * log2(e): folds softmax scale and exp->exp2 into the Q pack.
#define QSCALE 0.18033688011112042f

__device__ __forceinline__ unsigned short f2bf(float x) {
    unsigned int u = __builtin_bit_cast(unsigned int, x);
    u = (u + 0x7FFFu + ((u >> 16) & 1u)) >> 16;
    return (unsigned short)u;
}

__device__ __forceinline__ void gload_lds16(const unsigned short* g, unsigned short* l) {
    __builtin_amdgcn_global_load_lds((AS1 void*)g, (AS3 void*)l, 16, 0, 0);
}

// ================= prep: conv_x + rope_tab + 2x wtrans in ONE launch =================
__device__ void wtrans_body(const float* __restrict__ wsrc, unsigned short* __restrict__ wt,
                            int K, int N, int bx, int by, float (*T)[65])
{
    const int tid = threadIdx.x;
    const int k0 = by * 64, n0 = bx * 64;
    #pragma unroll
    for (int rnd = 0; rnd < 4; ++rnd) {
        int row = (tid >> 4) + rnd * 16;
        int c = (tid & 15) * 4;
        float4 v = *(const float4*)&wsrc[(size_t)(k0 + row) * N + n0 + c];
        T[row][c] = v.x; T[row][c+1] = v.y; T[row][c+2] = v.z; T[row][c+3] = v.w;
    }
    __syncthreads();
    const int sr = tid >> 3, sc = (tid & 7) << 3;
    #pragma unroll
    for (int half = 0; half < 2; ++half) {
        int n = sr + half * 32;
        union { unsigned short u[8]; bf16x8 v; } pk;
        #pragma unroll
        for (int j = 0; j < 8; ++j) pk.u[j] = f2bf(T[sc + j][n]);
        *(bf16x8*)&wt[(size_t)(n0 + n) * K + k0 + sc] = pk.v;
    }
}

__global__ __launch_bounds__(256) void prep(const float* __restrict__ x,
                                            const float* __restrict__ rot,
                                            const float* __restrict__ w_qkv,
                                            const float* __restrict__ w_out,
                                            unsigned short* __restrict__ xb,
                                            float2* __restrict__ ctab,
                                            unsigned short* __restrict__ wqkvT,
                                            unsigned short* __restrict__ woutT)
{
    __shared__ float T[64][65];
    const int bid = blockIdx.x;
    if (bid < 2048) {
        size_t i = ((size_t)bid * 256 + threadIdx.x) * 8;
        float4 a = *(const float4*)&x[i];
        float4 b = *(const float4*)&x[i + 4];
        union { unsigned short u[8]; bf16x8 v; } pk;
        pk.u[0] = f2bf(a.x); pk.u[1] = f2bf(a.y); pk.u[2] = f2bf(a.z); pk.u[3] = f2bf(a.w);
        pk.u[4] = f2bf(b.x); pk.u[5] = f2bf(b.y); pk.u[6] = f2bf(b.z); pk.u[7] = f2bf(b.w);
        *(bf16x8*)&xb[i] = pk.v;
    } else if (bid < 2560) {
        int i = (bid - 2048) * 256 + threadIdx.x;   // SEQ*DH = 131072
        float r = rot[i];
        float s, c;
        __sincosf(r, &s, &c);
        ctab[i] = make_float2(c, s);
    } else if (bid < 3328) {
        int idx = bid - 2560;                       // 48 x 16
        wtrans_body(w_qkv, wqkvT, 1024, 3072, idx % 48, idx / 48, T);
    } else {
        int idx = bid - 3328;                       // 16 x 16
        wtrans_body(w_out, woutT, 1024, 1024, idx % 16, idx / 16, T);
    }
}

// ========== QKV GEMM v5: LDS-staged A/B, BK=64, 2-barrier loop (unchanged from r6) ==========
// V written TILED+SWIZZLED: vt[bh][t][d][ks'] with ks' = ((ks>>2) ^ (d&7))<<2.
__global__ __launch_bounds__(256, 5) void gemm_qkv(const unsigned short* __restrict__ A,
                                                   const unsigned short* __restrict__ Bt,
                                                   const float2* __restrict__ ctab,
                                                   unsigned short* __restrict__ qb,
                                                   unsigned short* __restrict__ kb,
                                                   unsigned short* __restrict__ vt)
{
    __shared__ __align__(16) unsigned short As[128 * 64];   // 16 KB, row-XOR swizzled
    __shared__ __align__(16) unsigned short Bs[64 * 64];    // 8 KB
    const int tid = threadIdx.x;
    const int w = tid >> 6, lane = tid & 63;
    const int quad = lane >> 4, lm = lane & 15;
    const int wr = w * 32;                                  // wave rows [wr, wr+32)
    const int bm = blockIdx.y * 128, bn = blockIdx.x * 64;

    // staging constants (attn9 pattern): each gload covers 32 rows x 64 cols
    const int ga = w * 8 + (lane >> 3);                     // row within 32-row group
    const int gp = ((lane & 7) ^ (lane >> 3)) << 3;         // pre-swizzled source chunk

    // fragment read chunk offsets for the two K=32 halves
    int cko[2];
    #pragma unroll
    for (int c = 0; c < 2; ++c)
        cko[c] = (((c * 4 + quad) ^ (lm & 7)) << 3);

    f32x4 acc[2][4];
    #pragma unroll
    for (int i = 0; i < 2; ++i)
        #pragma unroll
        for (int j = 0; j < 4; ++j) acc[i][j] = (f32x4){0.f, 0.f, 0.f, 0.f};

    for (int k0 = 0; k0 < 1024; k0 += 64) {
        __syncthreads();
        #pragma unroll
        for (int i = 0; i < 4; ++i)
            gload_lds16(&A[(size_t)(bm + i * 32 + ga) * 1024 + k0 + gp], As + i * 2048 + w * 512);
        #pragma unroll
        for (int i = 0; i < 2; ++i)
            gload_lds16(&Bt[(size_t)(bn + i * 32 + ga) * 1024 + k0 + gp], Bs + i * 2048 + w * 512);
        __syncthreads();
        bf16x8 af[2][2], bfr[4][2];
        #pragma unroll
        for (int mt = 0; mt < 2; ++mt)
            #pragma unroll
            for (int c = 0; c < 2; ++c)
                af[mt][c] = *(const bf16x8*)&As[(wr + mt * 16 + lm) * 64 + cko[c]];
        #pragma unroll
        for (int nt = 0; nt < 4; ++nt)
            #pragma unroll
            for (int c = 0; c < 2; ++c)
                bfr[nt][c] = *(const bf16x8*)&Bs[(nt * 16 + lm) * 64 + cko[c]];
        #pragma unroll
        for (int mt = 0; mt < 2; ++mt)
            #pragma unroll
            for (int nt = 0; nt < 4; ++nt) {
                acc[mt][nt] = __builtin_amdgcn_mfma_f32_16x16x32_bf16(af[mt][0], bfr[nt][0], acc[mt][nt], 0, 0, 0);
                acc[mt][nt] = __builtin_amdgcn_mfma_f32_16x16x32_bf16(af[mt][1], bfr[nt][1], acc[mt][nt], 0, 0, 0);
            }
    }

    const int colbase = bn;                // 64-col block = one (region, head) slice
    const int region = colbase >> 10;      // 0=q, 1=k, 2=v
    const int h = (colbase >> 6) & 15;

    if (region == 2) {
        #pragma unroll
        for (int mt = 0; mt < 2; ++mt) {
            int rowb = bm + wr + mt * 16 + quad * 4;
            int b = rowb >> 11, seq = rowb & (SEQ - 1);
            int t = seq >> 5, ks = seq & 31;            // ks is a multiple of 4
            #pragma unroll
            for (int nt = 0; nt < 4; ++nt) {
                int d = nt * 16 + lm;
                int ksw = (((ks >> 2) ^ (lm & 7)) << 2);   // slot-level XOR swizzle
                ushort4 pk;
                pk.x = f2bf(acc[mt][nt][0]); pk.y = f2bf(acc[mt][nt][1]);
                pk.z = f2bf(acc[mt][nt][2]); pk.w = f2bf(acc[mt][nt][3]);
                *(ushort4*)&vt[(((size_t)(b * HEADS + h) * 64 + t) * 64 + d) * 32 + ksw] = pk;
            }
        }
    } else {
        const float qs = (region == 0) ? QSCALE : 1.0f;
        unsigned short* dst = (region == 0) ? qb : kb;
        #pragma unroll
        for (int mt = 0; mt < 2; ++mt) {
            #pragma unroll
            for (int nt = 0; nt < 2; ++nt) {
                int d = nt * 16 + lm;
                #pragma unroll
                for (int r = 0; r < 4; ++r) {
                    int row = bm + wr + mt * 16 + quad * 4 + r;
                    int b = row >> 11, seq = row & (SEQ - 1);
                    float2 cs0 = ctab[seq * DH + d];
                    float2 cs1 = ctab[seq * DH + d + 32];
                    float x0 = acc[mt][nt][r];
                    float x1 = acc[mt][nt + 2][r];
                    size_t ob = ((size_t)(b * HEADS + h) * SEQ + seq) * DH;
                    dst[ob + d]      = f2bf((x0 * cs0.x - x1 * cs0.y) * qs);
                    dst[ob + d + 32] = f2bf((x1 * cs1.x + x0 * cs1.y) * qs);
                }
            }
        }
    }
}

// ========== Flash attention v13 (r6 exact text, NO setprio — r7 A/B isolation) ==========
// r7 tripwire: absmax passed but launch_once diverged from graph = intermittent race
// introduced in r7. Suspects: setprio (m152 precedent: technique combos race) vs
// gemm_out v4 (inspection-clean, isomorphic to passing gemm_qkv v5). This round drops
// setprio and keeps gemm_out v4 to isolate the racer.
__global__ __launch_bounds__(256, 4) void attn13(const unsigned short* __restrict__ qb,
                                                 const unsigned short* __restrict__ kb,
                                                 const unsigned short* __restrict__ vt,
                                                 unsigned short* __restrict__ attnb)
{
    __shared__ __align__(16) char smem[32768];
    unsigned short* Ks = (unsigned short*)smem;             // [2 buf][64 kseq][64 d] swizzled rows
    unsigned short* Vs = (unsigned short*)(smem + 16384);   // [2 buf][2 t][64 d][32 ks'] slot-swizzled

    const int tid = threadIdx.x;
    const int w = tid >> 6, lane = tid & 63, quad = lane >> 4, lm = lane & 15;
    const int qg = w >> 1, kg = w & 1;

    // XCD-aware remap: all 32 q-tiles of one bh land on one XCD (linear L = x + 32y).
    // Per-XCD K/V working set = 4 bh x 512 KB = 2 MB < 4 MB L2.
    const int L = blockIdx.x + blockIdx.y * 32;
    const int bh = (L & 7) + 8 * ((L >> 3) & 3);
    const int q0 = (L >> 5) * 64;

    const int b = bh >> 4, h = bh & 15;
    const size_t hb = (size_t)bh * SEQ * DH;

    // Q fragments: wave's 32 q rows (B-operand: lane q=lm, k = c*32+quad*8+j)
    bf16x8 qf[2][2];
    #pragma unroll
    for (int qt = 0; qt < 2; ++qt)
        #pragma unroll
        for (int c = 0; c < 2; ++c)
            qf[qt][c] = *(const bf16x8*)&qb[hb + (size_t)(q0 + qg * 32 + qt * 16 + lm) * DH + c * 32 + quad * 8];

    // --- staging lane constants (identical to attn9) ---
    const int r0 = (w * 16) + (lane >> 3);
    const int p0 = lane & 7;
    const int gk0 = r0 * 64 + (p0 ^ (r0 & 7)) * 8;          // pre-swizzled global src, n=0
    const int r1 = r0 + 8;
    const int gk1 = r1 * 64 + (p0 ^ (r1 & 7)) * 8;          // n=1
    const unsigned short* kgp = kb + hb;
    const unsigned short* vgp = vt + hb;                     // tiled+swizzled [t][64][32]
    const int gv0 = w * 1024 + lane * 8;
    const int gv1 = gv0 + 512;
    unsigned short* kdst0 = Ks + w * 1024;
    unsigned short* kdst1 = Ks + w * 1024 + 512;
    unsigned short* vdst0 = Vs + w * 1024;
    unsigned short* vdst1 = Vs + w * 1024 + 512;

    // --- frag read offsets (elements, relative to buffer base) ---
    int kfo[2];
    #pragma unroll
    for (int c = 0; c < 2; ++c)
        kfo[c] = (kg * 32 + lm) * 64 + (((c * 4 + quad) ^ (lm & 7)) * 8);
    const int vrow = kg * 2048 + lm * 32;                    // + dt*512 + swizzled slot

    float rs[2] = {0.f, 0.f};
    f32x4 o[2][4];
    #pragma unroll
    for (int qt = 0; qt < 2; ++qt)
        #pragma unroll
        for (int dt = 0; dt < 4; ++dt) o[qt][dt] = (f32x4){0.f, 0.f, 0.f, 0.f};

    // prime: DMA tile 0 into buf 0
    gload_lds16(kgp + gk0, kdst0);
    gload_lds16(kgp + gk1, kdst1);
    gload_lds16(vgp + gv0, vdst0);
    gload_lds16(vgp + gv1, vdst1);

    #pragma unroll 2
    for (int it = 0; it < 32; ++it) {
        const int buf = it & 1;
        __syncthreads();   // drains vmcnt(0): DMA(it) visible; buf^1 free to overwrite
        {
            const size_t nb = (size_t)((it + 1) & 31) * 4096;  // tile base in elements
            const int bo = (buf ^ 1) * 4096;
            gload_lds16(kgp + nb + gk0, kdst0 + bo);
            gload_lds16(kgp + nb + gk1, kdst1 + bo);
            gload_lds16(vgp + nb + gv0, vdst0 + bo);
            gload_lds16(vgp + nb + gv1, vdst1 + bo);
        }
        const unsigned short* Kb = Ks + buf * 4096;
        const unsigned short* Vb = Vs + buf * 4096;

        #pragma unroll
        for (int kt = 0; kt < 2; ++kt) {
            bf16x8 k0 = *(const bf16x8*)&Kb[kfo[0] + kt * 1024];
            bf16x8 k1 = *(const bf16x8*)&Kb[kfo[1] + kt * 1024];
            bf16x4 vb[4];
            #pragma unroll
            for (int dt = 0; dt < 4; ++dt)
                vb[dt] = *(const bf16x4*)&Vb[vrow + dt * 512 + (((kt * 4 + quad) ^ (lm & 7)) << 2)];
            f32x4 s[2];
            #pragma unroll
            for (int qt = 0; qt < 2; ++qt) {
                f32x4 z = (f32x4){0.f, 0.f, 0.f, 0.f};
                z = __builtin_amdgcn_mfma_f32_16x16x32_bf16(k0, qf[qt][0], z, 0, 0, 0);
                s[qt] = __builtin_amdgcn_mfma_f32_16x16x32_bf16(k1, qf[qt][1], z, 0, 0, 0);
            }
            #pragma unroll
            for (int qt = 0; qt < 2; ++qt) {
                unsigned int u[4];
                #pragma unroll
                for (int r = 0; r < 4; ++r) {
                    float p = __builtin_amdgcn_exp2f(s[qt][r]);
                    rs[qt] += p;
                    u[r] = __builtin_bit_cast(unsigned int, p);
                }
                union { unsigned int w2[2]; bf16x4 v; } pk;
                pk.w2[0] = __builtin_amdgcn_perm(u[1], u[0], 0x07060302);
                pk.w2[1] = __builtin_amdgcn_perm(u[3], u[2], 0x07060302);
                // P fragment is already in A-operand layout for K=16 MFMA: row=q=lm,
                // k=quad*4+{0..3}. Accumulate PV directly, no LDS round-trip.
                #pragma unroll
                for (int dt = 0; dt < 4; ++dt)
                    o[qt][dt] = __builtin_amdgcn_mfma_f32_16x16x16bf16_1k(pk.v, vb[dt], o[qt][dt], 0, 0, 0);
            }
        }
    }

    // quad-reduce rs (full row-sum for q=lm in every lane)
    #pragma unroll
    for (int off = 16; off < 64; off <<= 1)
        #pragma unroll
        for (int qt = 0; qt < 2; ++qt) rs[qt] += __shfl_xor(rs[qt], off, 64);

    // ---- merge the 2 k-groups (linear softmax: plain add) ----
    __syncthreads();   // drains last dummy DMA before overlaying smem
    float* oBuf = (float*)smem;                  // [64 q][68] floats = 17408 B (overlays Ks/Vs)
    float* lRed = (float*)(smem + 17408);        // [64]
    if (kg == 1) {
        #pragma unroll
        for (int qt = 0; qt < 2; ++qt)
            #pragma unroll
            for (int dt = 0; dt < 4; ++dt)
                #pragma unroll
                for (int r = 0; r < 4; ++r)
                    oBuf[(qg * 32 + qt * 16 + quad * 4 + r) * 68 + dt * 16 + lm] = o[qt][dt][r];
        if (quad == 0) {
            #pragma unroll
            for (int qt = 0; qt < 2; ++qt) lRed[qg * 32 + qt * 16 + lm] = rs[qt];
        }
    }
    __syncthreads();
    if (kg == 0) {
        #pragma unroll
        for (int qt = 0; qt < 2; ++qt) {
            rs[qt] += lRed[qg * 32 + qt * 16 + lm];
            #pragma unroll
            for (int dt = 0; dt < 4; ++dt)
                #pragma unroll
                for (int r = 0; r < 4; ++r)
                    o[qt][dt][r] += oBuf[(qg * 32 + qt * 16 + quad * 4 + r) * 68 + dt * 16 + lm];
        }
        #pragma unroll
        for (int qt = 0; qt < 2; ++qt)
            #pragma unroll
            for (int r = 0; r < 4; ++r) {
                float inv = 1.0f / __shfl(rs[qt], quad * 4 + r, 64);
                int row = b * SEQ + q0 + qg * 32 + qt * 16 + quad * 4 + r;
                #pragma unroll
                for (int dt = 0; dt < 4; ++dt)
                    attnb[(size_t)row * HID + h * DH + dt * 16 + lm] = f2bf(o[qt][dt][r] * inv);
            }
    }
}

// ========== output GEMM v4: gemm_qkv-v5 structure (BK=64, 2-barrier, 8-chunk swizzle) ==========
// 64x64 tile, BK=64, 16 iters, 8 MFMA/iter/wave, conflict-free XOR staging,
// single-buffer 2-barrier loop. 16 KB LDS, 4 blocks/CU, grid 1024 = exact fit.
__global__ __launch_bounds__(256, 4) void gemm_out(const unsigned short* __restrict__ A,
                                                   const unsigned short* __restrict__ Bt,
                                                   float* __restrict__ C)
{
    __shared__ __align__(16) unsigned short As[64 * 64];    // 8 KB
    __shared__ __align__(16) unsigned short Bs[64 * 64];    // 8 KB
    const int tid = threadIdx.x;
    const int w = tid >> 6, lane = tid & 63;
    const int quad = lane >> 4, lm = lane & 15;
    const int wr = w * 16;                                  // wave rows [wr, wr+16)
    const int bm = blockIdx.y * 64, bn = blockIdx.x * 64;

    const int ga = w * 8 + (lane >> 3);                     // row within 32-row group
    const int gp = ((lane & 7) ^ (lane >> 3)) << 3;         // pre-swizzled source chunk

    int cko[2];
    #pragma unroll
    for (int c = 0; c < 2; ++c)
        cko[c] = (((c * 4 + quad) ^ (lm & 7)) << 3);

    f32x4 acc[4];
    #pragma unroll
    for (int j = 0; j < 4; ++j) acc[j] = (f32x4){0.f, 0.f, 0.f, 0.f};

    for (int k0 = 0; k0 < 1024; k0 += 64) {
        __syncthreads();
        #pragma unroll
        for (int i = 0; i < 2; ++i)
            gload_lds16(&A [(size_t)(bm + i * 32 + ga) * 1024 + k0 + gp], As + i * 2048 + w * 512);
        #pragma unroll
        for (int i = 0; i < 2; ++i)
            gload_lds16(&Bt[(size_t)(bn + i * 32 + ga) * 1024 + k0 + gp], Bs + i * 2048 + w * 512);
        __syncthreads();
        bf16x8 af[2], bfr[4][2];
        #pragma unroll
        for (int c = 0; c < 2; ++c)
            af[c] = *(const bf16x8*)&As[(wr + lm) * 64 + cko[c]];
        #pragma unroll
        for (int nt = 0; nt < 4; ++nt)
            #pragma unroll
            for (int c = 0; c < 2; ++c)
                bfr[nt][c] = *(const bf16x8*)&Bs[(nt * 16 + lm) * 64 + cko[c]];
        #pragma unroll
        for (int nt = 0; nt < 4; ++nt) {
            acc[nt] = __builtin_amdgcn_mfma_f32_16x16x32_bf16(af[0], bfr[nt][0], acc[nt], 0, 0, 0);
            acc[nt] = __builtin_amdgcn_mfma_f32_16x16x32_bf16(af[1], bfr[nt][1], acc[nt], 0, 0, 0);
        }
    }

    #pragma unroll
    for (int nt = 0; nt < 4; ++nt) {
        int col = bn + nt * 16 + lm;
        #pragma unroll
        for (int r = 0; r < 4; ++r) {
            int row = bm + wr + quad * 4 + r;
            C[(size_t)row * 1024 + col] = acc[nt][r];
        }
    }
}

extern "C" void kernel_launch(void* const* d_in, const int* in_sizes, int n_in,
                              void* d_out, int out_size, void* d_ws, size_t ws_size,
                              hipStream_t stream) {
    const float* x     = (const float*)d_in[0];
    const float* rot   = (const float*)d_in[1];
    const float* w_qkv = (const float*)d_in[2];
    const float* w_out = (const float*)d_in[3];
    float* out = (float*)d_out;

    char* ws = (char*)d_ws;
    unsigned short* xb    = (unsigned short*)(ws);                         // 8 MB
    unsigned short* qb    = (unsigned short*)(ws + (size_t)( 8u << 20));   // 8 MB [bh][seq][64]
    unsigned short* kb    = (unsigned short*)(ws + (size_t)(16u << 20));   // 8 MB [bh][seq][64]
    unsigned short* vt    = (unsigned short*)(ws + (size_t)(24u << 20));   // 8 MB [bh][seq/32][64][32] slot-swizzled
    unsigned short* attnb = (unsigned short*)(ws + (size_t)(32u << 20));   // 8 MB
    unsigned short* wqkvT = (unsigned short*)(ws + (size_t)(40u << 20));   // 6 MB
    unsigned short* woutT = (unsigned short*)(ws + (size_t)(46u << 20));   // 2 MB
    float2*         ctab  = (float2*)        (ws + (size_t)(48u << 20));   // 1 MB

    prep<<<3584, 256, 0, stream>>>(x, rot, w_qkv, w_out, xb, ctab, wqkvT, woutT);

    gemm_qkv<<<dim3(48, 32), 256, 0, stream>>>(xb, wqkvT, ctab, qb, kb, vt);

    attn13<<<dim3(32, 32), 256, 0, stream>>>(qb, kb, vt, attnb);

    gemm_out<<<dim3(16, 64), 256, 0, stream>>>(attnb, woutT, out);
}

// Round 11
// 173.149 us; speedup vs baseline: 1.1931x; 1.0312x over previous
//
#include <hip/hip_runtime.h>
#include <math.h>

#define HEADS 16
#define DH    64
#define SEQ   2048
#define HID   1024
#define NROW  4096

typedef __attribute__((ext_vector_type(8))) short bf16x8;
typedef __attribute__((ext_vector_type(4))) short bf16x4;
typedef __attribute__((ext_vector_type(4))) float f32x4;

#define AS1 __attribute__((address_space(1)))
#define AS3 __attribute__((address_space(3)))

// 0.125 * log2(e): folds softmax scale and exp->exp2 into the Q pack.
#define QSCALE 0.18033688011112042f

__device__ __forceinline__ unsigned short f2bf(float x) {
    unsigned int u = __builtin_bit_cast(unsigned int, x);
    u = (u + 0x7FFFu + ((u >> 16) & 1u)) >> 16;
    return (unsigned short)u;
}

__device__ __forceinline__ void gload_lds16(const unsigned short* g, unsigned short* l) {
    __builtin_amdgcn_global_load_lds((AS1 void*)g, (AS3 void*)l, 16, 0, 0);
}

// ================= prep: conv_x + rope_tab + 2x wtrans in ONE launch =================
__device__ void wtrans_body(const float* __restrict__ wsrc, unsigned short* __restrict__ wt,
                            int K, int N, int bx, int by, float (*T)[65])
{
    const int tid = threadIdx.x;
    const int k0 = by * 64, n0 = bx * 64;
    #pragma unroll
    for (int rnd = 0; rnd < 4; ++rnd) {
        int row = (tid >> 4) + rnd * 16;
        int c = (tid & 15) * 4;
        float4 v = *(const float4*)&wsrc[(size_t)(k0 + row) * N + n0 + c];
        T[row][c] = v.x; T[row][c+1] = v.y; T[row][c+2] = v.z; T[row][c+3] = v.w;
    }
    __syncthreads();
    const int sr = tid >> 3, sc = (tid & 7) << 3;
    #pragma unroll
    for (int half = 0; half < 2; ++half) {
        int n = sr + half * 32;
        union { unsigned short u[8]; bf16x8 v; } pk;
        #pragma unroll
        for (int j = 0; j < 8; ++j) pk.u[j] = f2bf(T[sc + j][n]);
        *(bf16x8*)&wt[(size_t)(n0 + n) * K + k0 + sc] = pk.v;
    }
}

__global__ __launch_bounds__(256) void prep(const float* __restrict__ x,
                                            const float* __restrict__ rot,
                                            const float* __restrict__ w_qkv,
                                            const float* __restrict__ w_out,
                                            unsigned short* __restrict__ xb,
                                            float2* __restrict__ ctab,
                                            unsigned short* __restrict__ wqkvT,
                                            unsigned short* __restrict__ woutT)
{
    __shared__ float T[64][65];
    const int bid = blockIdx.x;
    if (bid < 2048) {
        size_t i = ((size_t)bid * 256 + threadIdx.x) * 8;
        float4 a = *(const float4*)&x[i];
        float4 b = *(const float4*)&x[i + 4];
        union { unsigned short u[8]; bf16x8 v; } pk;
        pk.u[0] = f2bf(a.x); pk.u[1] = f2bf(a.y); pk.u[2] = f2bf(a.z); pk.u[3] = f2bf(a.w);
        pk.u[4] = f2bf(b.x); pk.u[5] = f2bf(b.y); pk.u[6] = f2bf(b.z); pk.u[7] = f2bf(b.w);
        *(bf16x8*)&xb[i] = pk.v;
    } else if (bid < 2560) {
        int i = (bid - 2048) * 256 + threadIdx.x;   // SEQ*DH = 131072
        float r = rot[i];
        float s, c;
        __sincosf(r, &s, &c);
        ctab[i] = make_float2(c, s);
    } else if (bid < 3328) {
        int idx = bid - 2560;                       // 48 x 16
        wtrans_body(w_qkv, wqkvT, 1024, 3072, idx % 48, idx / 48, T);
    } else {
        int idx = bid - 3328;                       // 16 x 16
        wtrans_body(w_out, woutT, 1024, 1024, idx % 16, idx / 16, T);
    }
}

// ========== QKV GEMM v6: 128x128 tile, 2x2 wave grid (64x64/wave) — LDS-reuse fix ==========
// r8 diagnosis: v5 was LDS-read-BW bound: 12 ds_read_b128 per wave-iter feeding 16 MFMAs
// (reuse 2.67); total ~1.8 GB LDS traffic ~ 26 us floor. v6: each wave computes 64x64
// (4mt x 4nt): 16 reads feed 32 MFMAs (reuse 4.0) -> ~1.2 GB. Same BK=64, same 2-barrier
// single-buffer loop, same XOR swizzle (row&7 == lm&7 for all fragment rows). Grid 24x32
// = 768 blocks = 3/CU @ 32 KB LDS. Epilogue unchanged: each wave's 64-col slice is one
// (region, head); colbase = bn + wcol.
// V written TILED+SWIZZLED: vt[bh][t][d][ks'] with ks' = ((ks>>2) ^ (d&7))<<2.
__global__ __launch_bounds__(256, 3) void gemm_qkv(const unsigned short* __restrict__ A,
                                                   const unsigned short* __restrict__ Bt,
                                                   const float2* __restrict__ ctab,
                                                   unsigned short* __restrict__ qb,
                                                   unsigned short* __restrict__ kb,
                                                   unsigned short* __restrict__ vt)
{
    __shared__ __align__(16) unsigned short As[128 * 64];   // 16 KB, chunk-XOR swizzled
    __shared__ __align__(16) unsigned short Bs[128 * 64];   // 16 KB
    const int tid = threadIdx.x;
    const int w = tid >> 6, lane = tid & 63;
    const int quad = lane >> 4, lm = lane & 15;
    const int wrow = (w >> 1) * 64, wcol = (w & 1) * 64;
    const int bm = blockIdx.y * 128, bn = blockIdx.x * 128;

    // staging constants: each gload line covers 32 rows x 64 cols (8 rows/wave)
    const int ga = w * 8 + (lane >> 3);                     // row within 32-row group
    const int gp = ((lane & 7) ^ (lane >> 3)) << 3;         // pre-swizzled source chunk

    // fragment read chunk offsets for the two K=32 halves
    int cko[2];
    #pragma unroll
    for (int c = 0; c < 2; ++c)
        cko[c] = (((c * 4 + quad) ^ (lm & 7)) << 3);

    f32x4 acc[4][4];
    #pragma unroll
    for (int i = 0; i < 4; ++i)
        #pragma unroll
        for (int j = 0; j < 4; ++j) acc[i][j] = (f32x4){0.f, 0.f, 0.f, 0.f};

    for (int k0 = 0; k0 < 1024; k0 += 64) {
        __syncthreads();
        #pragma unroll
        for (int i = 0; i < 4; ++i)
            gload_lds16(&A [(size_t)(bm + i * 32 + ga) * 1024 + k0 + gp], As + i * 2048 + w * 512);
        #pragma unroll
        for (int i = 0; i < 4; ++i)
            gload_lds16(&Bt[(size_t)(bn + i * 32 + ga) * 1024 + k0 + gp], Bs + i * 2048 + w * 512);
        __syncthreads();
        bf16x8 af[4][2], bfr[4][2];
        #pragma unroll
        for (int mt = 0; mt < 4; ++mt)
            #pragma unroll
            for (int c = 0; c < 2; ++c)
                af[mt][c] = *(const bf16x8*)&As[(wrow + mt * 16 + lm) * 64 + cko[c]];
        #pragma unroll
        for (int nt = 0; nt < 4; ++nt)
            #pragma unroll
            for (int c = 0; c < 2; ++c)
                bfr[nt][c] = *(const bf16x8*)&Bs[(wcol + nt * 16 + lm) * 64 + cko[c]];
        #pragma unroll
        for (int mt = 0; mt < 4; ++mt)
            #pragma unroll
            for (int nt = 0; nt < 4; ++nt) {
                acc[mt][nt] = __builtin_amdgcn_mfma_f32_16x16x32_bf16(af[mt][0], bfr[nt][0], acc[mt][nt], 0, 0, 0);
                acc[mt][nt] = __builtin_amdgcn_mfma_f32_16x16x32_bf16(af[mt][1], bfr[nt][1], acc[mt][nt], 0, 0, 0);
            }
    }

    const int colbase = bn + wcol;         // wave's 64-col slice = one (region, head)
    const int region = colbase >> 10;      // 0=q, 1=k, 2=v
    const int h = (colbase >> 6) & 15;

    if (region == 2) {
        #pragma unroll
        for (int mt = 0; mt < 4; ++mt) {
            int rowb = bm + wrow + mt * 16 + quad * 4;
            int b = rowb >> 11, seq = rowb & (SEQ - 1);
            int t = seq >> 5, ks = seq & 31;            // ks is a multiple of 4
            #pragma unroll
            for (int nt = 0; nt < 4; ++nt) {
                int d = nt * 16 + lm;
                int ksw = (((ks >> 2) ^ (lm & 7)) << 2);   // slot-level XOR swizzle
                ushort4 pk;
                pk.x = f2bf(acc[mt][nt][0]); pk.y = f2bf(acc[mt][nt][1]);
                pk.z = f2bf(acc[mt][nt][2]); pk.w = f2bf(acc[mt][nt][3]);
                *(ushort4*)&vt[(((size_t)(b * HEADS + h) * 64 + t) * 64 + d) * 32 + ksw] = pk;
            }
        }
    } else {
        const float qs = (region == 0) ? QSCALE : 1.0f;
        unsigned short* dst = (region == 0) ? qb : kb;
        #pragma unroll
        for (int mt = 0; mt < 4; ++mt) {
            #pragma unroll
            for (int nt = 0; nt < 2; ++nt) {
                int d = nt * 16 + lm;
                #pragma unroll
                for (int r = 0; r < 4; ++r) {
                    int row = bm + wrow + mt * 16 + quad * 4 + r;
                    int b = row >> 11, seq = row & (SEQ - 1);
                    float2 cs0 = ctab[seq * DH + d];
                    float2 cs1 = ctab[seq * DH + d + 32];
                    float x0 = acc[mt][nt][r];
                    float x1 = acc[mt][nt + 2][r];
                    size_t ob = ((size_t)(b * HEADS + h) * SEQ + seq) * DH;
                    dst[ob + d]      = f2bf((x0 * cs0.x - x1 * cs0.y) * qs);
                    dst[ob + d + 32] = f2bf((x1 * cs1.x + x0 * cs1.y) * qs);
                }
            }
        }
    }
}

// ========== Flash attention v13 (unchanged from r8 passing config) ==========
__global__ __launch_bounds__(256, 4) void attn13(const unsigned short* __restrict__ qb,
                                                 const unsigned short* __restrict__ kb,
                                                 const unsigned short* __restrict__ vt,
                                                 unsigned short* __restrict__ attnb)
{
    __shared__ __align__(16) char smem[32768];
    unsigned short* Ks = (unsigned short*)smem;             // [2 buf][64 kseq][64 d] swizzled rows
    unsigned short* Vs = (unsigned short*)(smem + 16384);   // [2 buf][2 t][64 d][32 ks'] slot-swizzled

    const int tid = threadIdx.x;
    const int w = tid >> 6, lane = tid & 63, quad = lane >> 4, lm = lane & 15;
    const int qg = w >> 1, kg = w & 1;

    // XCD-aware remap: all 32 q-tiles of one bh land on one XCD (linear L = x + 32y).
    // Per-XCD K/V working set = 4 bh x 512 KB = 2 MB < 4 MB L2.
    const int L = blockIdx.x + blockIdx.y * 32;
    const int bh = (L & 7) + 8 * ((L >> 3) & 3);
    const int q0 = (L >> 5) * 64;

    const int b = bh >> 4, h = bh & 15;
    const size_t hb = (size_t)bh * SEQ * DH;

    // Q fragments: wave's 32 q rows (B-operand: lane q=lm, k = c*32+quad*8+j)
    bf16x8 qf[2][2];
    #pragma unroll
    for (int qt = 0; qt < 2; ++qt)
        #pragma unroll
        for (int c = 0; c < 2; ++c)
            qf[qt][c] = *(const bf16x8*)&qb[hb + (size_t)(q0 + qg * 32 + qt * 16 + lm) * DH + c * 32 + quad * 8];

    // --- staging lane constants (identical to attn9) ---
    const int r0 = (w * 16) + (lane >> 3);
    const int p0 = lane & 7;
    const int gk0 = r0 * 64 + (p0 ^ (r0 & 7)) * 8;          // pre-swizzled global src, n=0
    const int r1 = r0 + 8;
    const int gk1 = r1 * 64 + (p0 ^ (r1 & 7)) * 8;          // n=1
    const unsigned short* kgp = kb + hb;
    const unsigned short* vgp = vt + hb;                     // tiled+swizzled [t][64][32]
    const int gv0 = w * 1024 + lane * 8;
    const int gv1 = gv0 + 512;
    unsigned short* kdst0 = Ks + w * 1024;
    unsigned short* kdst1 = Ks + w * 1024 + 512;
    unsigned short* vdst0 = Vs + w * 1024;
    unsigned short* vdst1 = Vs + w * 1024 + 512;

    // --- frag read offsets (elements, relative to buffer base) ---
    int kfo[2];
    #pragma unroll
    for (int c = 0; c < 2; ++c)
        kfo[c] = (kg * 32 + lm) * 64 + (((c * 4 + quad) ^ (lm & 7)) * 8);
    const int vrow = kg * 2048 + lm * 32;                    // + dt*512 + swizzled slot

    float rs[2] = {0.f, 0.f};
    f32x4 o[2][4];
    #pragma unroll
    for (int qt = 0; qt < 2; ++qt)
        #pragma unroll
        for (int dt = 0; dt < 4; ++dt) o[qt][dt] = (f32x4){0.f, 0.f, 0.f, 0.f};

    // prime: DMA tile 0 into buf 0
    gload_lds16(kgp + gk0, kdst0);
    gload_lds16(kgp + gk1, kdst1);
    gload_lds16(vgp + gv0, vdst0);
    gload_lds16(vgp + gv1, vdst1);

    #pragma unroll 2
    for (int it = 0; it < 32; ++it) {
        const int buf = it & 1;
        __syncthreads();   // drains vmcnt(0): DMA(it) visible; buf^1 free to overwrite
        {
            const size_t nb = (size_t)((it + 1) & 31) * 4096;  // tile base in elements
            const int bo = (buf ^ 1) * 4096;
            gload_lds16(kgp + nb + gk0, kdst0 + bo);
            gload_lds16(kgp + nb + gk1, kdst1 + bo);
            gload_lds16(vgp + nb + gv0, vdst0 + bo);
            gload_lds16(vgp + nb + gv1, vdst1 + bo);
        }
        const unsigned short* Kb = Ks + buf * 4096;
        const unsigned short* Vb = Vs + buf * 4096;

        #pragma unroll
        for (int kt = 0; kt < 2; ++kt) {
            bf16x8 k0 = *(const bf16x8*)&Kb[kfo[0] + kt * 1024];
            bf16x8 k1 = *(const bf16x8*)&Kb[kfo[1] + kt * 1024];
            bf16x4 vb[4];
            #pragma unroll
            for (int dt = 0; dt < 4; ++dt)
                vb[dt] = *(const bf16x4*)&Vb[vrow + dt * 512 + (((kt * 4 + quad) ^ (lm & 7)) << 2)];
            f32x4 s[2];
            #pragma unroll
            for (int qt = 0; qt < 2; ++qt) {
                f32x4 z = (f32x4){0.f, 0.f, 0.f, 0.f};
                z = __builtin_amdgcn_mfma_f32_16x16x32_bf16(k0, qf[qt][0], z, 0, 0, 0);
                s[qt] = __builtin_amdgcn_mfma_f32_16x16x32_bf16(k1, qf[qt][1], z, 0, 0, 0);
            }
            #pragma unroll
            for (int qt = 0; qt < 2; ++qt) {
                unsigned int u[4];
                #pragma unroll
                for (int r = 0; r < 4; ++r) {
                    float p = __builtin_amdgcn_exp2f(s[qt][r]);
                    rs[qt] += p;
                    u[r] = __builtin_bit_cast(unsigned int, p);
                }
                union { unsigned int w2[2]; bf16x4 v; } pk;
                pk.w2[0] = __builtin_amdgcn_perm(u[1], u[0], 0x07060302);
                pk.w2[1] = __builtin_amdgcn_perm(u[3], u[2], 0x07060302);
                // P fragment is already in A-operand layout for K=16 MFMA: row=q=lm,
                // k=quad*4+{0..3}. Accumulate PV directly, no LDS round-trip.
                #pragma unroll
                for (int dt = 0; dt < 4; ++dt)
                    o[qt][dt] = __builtin_amdgcn_mfma_f32_16x16x16bf16_1k(pk.v, vb[dt], o[qt][dt], 0, 0, 0);
            }
        }
    }

    // quad-reduce rs (full row-sum for q=lm in every lane)
    #pragma unroll
    for (int off = 16; off < 64; off <<= 1)
        #pragma unroll
        for (int qt = 0; qt < 2; ++qt) rs[qt] += __shfl_xor(rs[qt], off, 64);

    // ---- merge the 2 k-groups (linear softmax: plain add) ----
    __syncthreads();   // drains last dummy DMA before overlaying smem
    float* oBuf = (float*)smem;                  // [64 q][68] floats = 17408 B (overlays Ks/Vs)
    float* lRed = (float*)(smem + 17408);        // [64]
    if (kg == 1) {
        #pragma unroll
        for (int qt = 0; qt < 2; ++qt)
            #pragma unroll
            for (int dt = 0; dt < 4; ++dt)
                #pragma unroll
                for (int r = 0; r < 4; ++r)
                    oBuf[(qg * 32 + qt * 16 + quad * 4 + r) * 68 + dt * 16 + lm] = o[qt][dt][r];
        if (quad == 0) {
            #pragma unroll
            for (int qt = 0; qt < 2; ++qt) lRed[qg * 32 + qt * 16 + lm] = rs[qt];
        }
    }
    __syncthreads();
    if (kg == 0) {
        #pragma unroll
        for (int qt = 0; qt < 2; ++qt) {
            rs[qt] += lRed[qg * 32 + qt * 16 + lm];
            #pragma unroll
            for (int dt = 0; dt < 4; ++dt)
                #pragma unroll
                for (int r = 0; r < 4; ++r)
                    o[qt][dt][r] += oBuf[(qg * 32 + qt * 16 + quad * 4 + r) * 68 + dt * 16 + lm];
        }
        #pragma unroll
        for (int qt = 0; qt < 2; ++qt)
            #pragma unroll
            for (int r = 0; r < 4; ++r) {
                float inv = 1.0f / __shfl(rs[qt], quad * 4 + r, 64);
                int row = b * SEQ + q0 + qg * 32 + qt * 16 + quad * 4 + r;
                #pragma unroll
                for (int dt = 0; dt < 4; ++dt)
                    attnb[(size_t)row * HID + h * DH + dt * 16 + lm] = f2bf(o[qt][dt][r] * inv);
            }
    }
}

// ========== output GEMM v4 (unchanged from r8 passing config) ==========
__global__ __launch_bounds__(256, 4) void gemm_out(const unsigned short* __restrict__ A,
                                                   const unsigned short* __restrict__ Bt,
                                                   float* __restrict__ C)
{
    __shared__ __align__(16) unsigned short As[64 * 64];    // 8 KB
    __shared__ __align__(16) unsigned short Bs[64 * 64];    // 8 KB
    const int tid = threadIdx.x;
    const int w = tid >> 6, lane = tid & 63;
    const int quad = lane >> 4, lm = lane & 15;
    const int wr = w * 16;                                  // wave rows [wr, wr+16)
    const int bm = blockIdx.y * 64, bn = blockIdx.x * 64;

    const int ga = w * 8 + (lane >> 3);                     // row within 32-row group
    const int gp = ((lane & 7) ^ (lane >> 3)) << 3;         // pre-swizzled source chunk

    int cko[2];
    #pragma unroll
    for (int c = 0; c < 2; ++c)
        cko[c] = (((c * 4 + quad) ^ (lm & 7)) << 3);

    f32x4 acc[4];
    #pragma unroll
    for (int j = 0; j < 4; ++j) acc[j] = (f32x4){0.f, 0.f, 0.f, 0.f};

    for (int k0 = 0; k0 < 1024; k0 += 64) {
        __syncthreads();
        #pragma unroll
        for (int i = 0; i < 2; ++i)
            gload_lds16(&A [(size_t)(bm + i * 32 + ga) * 1024 + k0 + gp], As + i * 2048 + w * 512);
        #pragma unroll
        for (int i = 0; i < 2; ++i)
            gload_lds16(&Bt[(size_t)(bn + i * 32 + ga) * 1024 + k0 + gp], Bs + i * 2048 + w * 512);
        __syncthreads();
        bf16x8 af[2], bfr[4][2];
        #pragma unroll
        for (int c = 0; c < 2; ++c)
            af[c] = *(const bf16x8*)&As[(wr + lm) * 64 + cko[c]];
        #pragma unroll
        for (int nt = 0; nt < 4; ++nt)
            #pragma unroll
            for (int c = 0; c < 2; ++c)
                bfr[nt][c] = *(const bf16x8*)&Bs[(nt * 16 + lm) * 64 + cko[c]];
        #pragma unroll
        for (int nt = 0; nt < 4; ++nt) {
            acc[nt] = __builtin_amdgcn_mfma_f32_16x16x32_bf16(af[0], bfr[nt][0], acc[nt], 0, 0, 0);
            acc[nt] = __builtin_amdgcn_mfma_f32_16x16x32_bf16(af[1], bfr[nt][1], acc[nt], 0, 0, 0);
        }
    }

    #pragma unroll
    for (int nt = 0; nt < 4; ++nt) {
        int col = bn + nt * 16 + lm;
        #pragma unroll
        for (int r = 0; r < 4; ++r) {
            int row = bm + wr + quad * 4 + r;
            C[(size_t)row * 1024 + col] = acc[nt][r];
        }
    }
}

extern "C" void kernel_launch(void* const* d_in, const int* in_sizes, int n_in,
                              void* d_out, int out_size, void* d_ws, size_t ws_size,
                              hipStream_t stream) {
    const float* x     = (const float*)d_in[0];
    const float* rot   = (const float*)d_in[1];
    const float* w_qkv = (const float*)d_in[2];
    const float* w_out = (const float*)d_in[3];
    float* out = (float*)d_out;

    char* ws = (char*)d_ws;
    unsigned short* xb    = (unsigned short*)(ws);                         // 8 MB
    unsigned short* qb    = (unsigned short*)(ws + (size_t)( 8u << 20));   // 8 MB [bh][seq][64]
    unsigned short* kb    = (unsigned short*)(ws + (size_t)(16u << 20));   // 8 MB [bh][seq][64]
    unsigned short* vt    = (unsigned short*)(ws + (size_t)(24u << 20));   // 8 MB [bh][seq/32][64][32] slot-swizzled
    unsigned short* attnb = (unsigned short*)(ws + (size_t)(32u << 20));   // 8 MB
    unsigned short* wqkvT = (unsigned short*)(ws + (size_t)(40u << 20));   // 6 MB
    unsigned short* woutT = (unsigned short*)(ws + (size_t)(46u << 20));   // 2 MB
    float2*         ctab  = (float2*)        (ws + (size_t)(48u << 20));   // 1 MB

    prep<<<3584, 256, 0, stream>>>(x, rot, w_qkv, w_out, xb, ctab, wqkvT, woutT);

    gemm_qkv<<<dim3(24, 32), 256, 0, stream>>>(xb, wqkvT, ctab, qb, kb, vt);

    attn13<<<dim3(32, 32), 256, 0, stream>>>(qb, kb, vt, attnb);

    gemm_out<<<dim3(16, 64), 256, 0, stream>>>(attnb, woutT, out);
}